// Round 8
// baseline (55.247 us; speedup 1.0000x reference)
//
#include <hip/hip_runtime.h>

// Exact closed form via a 4-state Pauli transfer-matrix contraction.
// Math identical to the R7 HW-validated kernel (absmax 2.4e-4); R8 only
// vectorizes I/O (5x float2 load / 5x float2 store) and uses 256-thread blocks.
//
// Circuit: RX(x_j + w0_j) -> CNOT ring -> RX(w1_j) -> CNOT ring -> <Z_q>.
// Site c = 9 - qubit j. alpha_c = x[9-c]+w0[9-c]; beta_c = w1[9-c].
// Active-site transfer T_k (derived from the R3/R5-validated CNOT LUT):
//   T e_I = g_k e_Z ; T e_X = s_k e_Y ;
//   T e_Y = g_k*sy_{k-1} e_I - s_k*cz_{k-1} e_X ;
//   T e_Z = g_k*cz_{k-1} e_I + s_k*sy_{k-1} e_X
// Inactive site: e_Z -> cz_{k-1} e_Z (prefix scalar). Boundary rows as below.
// Cross-checks: w1=0 reproduces HW-verified double-ring sign rows
// 0x2FF (q=1), 0x2AA (q=9), 0x355 (q=0); q=1 full branch trace matches.

#define NQ 10

__global__ __launch_bounds__(256)
void qeval_kernel(const float* __restrict__ inputs,
                  const float* __restrict__ weights,
                  float* __restrict__ out, int B)
{
    const int b = blockIdx.x * 256 + threadIdx.x;
    if (b >= B) return;

    // vector load: 40 B per thread as 5x float2 (8B-aligned for every b)
    const float2* inp2 = (const float2*)(inputs + b * NQ);
    float x[NQ];
    #pragma unroll
    for (int h = 0; h < 5; ++h) {
        const float2 v = inp2[h];
        x[2*h] = v.x; x[2*h + 1] = v.y;
    }

    float cz[NQ], sy[NQ], g[NQ], s[NQ];
    #pragma unroll
    for (int c = 0; c < NQ; ++c) {
        const float a = x[9 - c] + weights[9 - c];                 // x + w0
        float sn, cs; __sincosf(a, &sn, &cs);
        cz[c] = cs; sy[c] = -sn;
        float sb, cb; __sincosf(weights[NQ + 9 - c], &sb, &cb);    // w1
        g[c] = cb; s[c] = sb;
    }

    // inactive-prefix products: pref[k] = cz0*...*cz[k-2], pref[1] = 1
    float pref[9];
    pref[1] = 1.f;
    #pragma unroll
    for (int k = 2; k <= 8; ++k) pref[k] = pref[k - 1] * cz[k - 2];

    // suffix columns C_u(k) = (T_8 ... T_k) e_u ; k=9 -> identity
    float CI[4] = {1.f, 0.f, 0.f, 0.f};
    float CX[4] = {0.f, 1.f, 0.f, 0.f};
    float CY[4] = {0.f, 0.f, 1.f, 0.f};
    float CZ[4] = {0.f, 0.f, 0.f, 1.f};

    float res[NQ];

    #pragma unroll
    for (int k = 8; k >= 1; --k) {
        const float a  = g[k] * sy[k - 1];
        const float bb = s[k] * cz[k - 1];
        const float d  = g[k] * cz[k - 1];
        const float e  = s[k] * sy[k - 1];
        float nI[4], nX[4], nY[4], nZ[4];
        #pragma unroll
        for (int j = 0; j < 4; ++j) {
            nI[j] = g[k] * CZ[j];
            nX[j] = s[k] * CY[j];
            nY[j] = a * CI[j] - bb * CX[j];
            nZ[j] = d * CI[j] + e * CX[j];
        }
        #pragma unroll
        for (int j = 0; j < 4; ++j) {
            CI[j] = nI[j]; CX[j] = nX[j]; CY[j] = nY[j]; CZ[j] = nZ[j];
        }
        // q = 9-k in 1..8: Z-column of G_k through step-9 boundary, x prefix
        res[9 - k] = pref[k] * ( g[9] * (cz[9]*CZ[0] + sy[8]*CZ[2] + cz[8]*CZ[3])
                               + s[9] * sy[9] * CZ[1] );
    }

    // q = 9 (sites 0 and 9 both active at step 0)
    {
        const float BZ_CI = cz[9]*CI[0] + sy[8]*CI[2] + cz[8]*CI[3];
        const float BY_CI = sy[9]*CI[1];
        const float BZ_CX = cz[9]*CX[0] + sy[8]*CX[2] + cz[8]*CX[3];
        const float BY_CX = sy[9]*CX[1];
        res[9] = g[0]*g[9]*BZ_CI + g[0]*s[9]*BY_CI
               + s[0]*g[9]*BY_CX - s[0]*s[9]*BZ_CX;
    }
    // q = 0 (site 9 inactive: m9 in {I, X})
    {
        const float BI_CZ = CZ[0] + cz[9]*sy[8]*CZ[2] + cz[9]*cz[8]*CZ[3];
        const float BX_CY = sy[9]*cz[8]*CY[2] - sy[9]*sy[8]*CY[3];
        res[0] = g[0]*BI_CZ + s[0]*BX_CY;
    }

    // vector store: 5x float2
    float2* out2 = (float2*)(out + b * NQ);
    #pragma unroll
    for (int h = 0; h < 5; ++h)
        out2[h] = make_float2(res[2*h], res[2*h + 1]);
}

extern "C" void kernel_launch(void* const* d_in, const int* in_sizes, int n_in,
                              void* d_out, int out_size, void* d_ws, size_t ws_size,
                              hipStream_t stream) {
    const float* inputs  = (const float*)d_in[0];
    const float* weights = (const float*)d_in[1];
    float* out = (float*)d_out;
    const int B = in_sizes[0] / NQ;            // 8192
    qeval_kernel<<<(B + 255) / 256, 256, 0, stream>>>(inputs, weights, out, B);
}